// Round 12
// baseline (240.614 us; speedup 1.0000x reference)
//
#include <hip/hip_runtime.h>

// ContextualAttention: out[b,c,p] = sum_k K[b,k,c] * softmax_k( K[b,:,:] @ F[b,:,p] )
// K = rowwise-normalized (F^T + eps). Flash-style fusion, bf16 MFMA, f32 accum.
// Round 11: r9 skeleton (q=128/block, 16 waves, producer/consumer, KT=64,
//   16x16x32 MFMA everywhere) but KA goes through L1->registers instead of
//   LDS: prep emits fragment-major KAF image; producer A-loads are coalesced
//   1KB/instr; the 4 qh-waves issue identical addresses -> L1 broadcast.
//   LDS holds only P (+lE). All barriers lgkm-only (no DMA to drain).

#define BATCH 8
#define CH 256
#define NPIX 4096
#define EPSV 1e-7f
#define L2E 1.4426950408889634f

using bf16x8 = __attribute__((ext_vector_type(8))) __bf16;
using bf16x4 = __attribute__((ext_vector_type(4))) __bf16;
using f32x4  = __attribute__((ext_vector_type(4))) float;

// all-role barrier: LDS ops drained (P visibility); register global loads are
// tracked by vmcnt on their consumers, nothing to drain at the barrier.
__device__ __forceinline__ void barrier_lgkm() {
  asm volatile("s_waitcnt lgkmcnt(0)\n"
               "s_barrier" ::: "memory");
}

// ============================================================================
// Prep: per (batch, 32-key tile): inv-norms, normalized bf16 K, two images:
//   KAF[b][jt][st][cf][krow 0..31][lg 0..3][16B]  (GEMM1 A-frag-major image)
//     jt = kt>>1, st = kt&1; element = K[k = st*32+krow][c = cf*32+lg*8+j]
//   KB[b][kt][256 c][32 k]: plain layout           (GEMM2 L2 image)
// ============================================================================
__global__ __launch_bounds__(256)
void ca_prep(const float* __restrict__ F, __bf16* __restrict__ KAF,
             __bf16* __restrict__ KB) {
  const int b   = blockIdx.x;
  const int kt  = blockIdx.y;          // 128 tiles of 32 keys
  const int kt0 = kt * 32;
  const int t   = threadIdx.x;
  const int k   = t & 31;
  const int h   = (t >> 5) & 1;
  const int w   = t >> 6;

  const float* __restrict__ Fb = F + (size_t)b * CH * NPIX;

  __shared__ float red[4][32];
  __shared__ float invk[32];
  __shared__ __align__(16) __bf16 T[32][264];   // +8 pad (528B rows, 16B mult)

  float fv[32];
  float ss = 0.f;
#pragma unroll
  for (int rep = 0; rep < 32; ++rep) {
    int c = rep * 8 + w * 2 + h;
    float v = Fb[(size_t)c * NPIX + kt0 + k] + EPSV;
    fv[rep] = v;
    ss = fmaf(v, v, ss);
  }
  ss += __shfl_xor(ss, 32, 64);
  if ((t & 32) == 0) red[w][k] = ss;
  __syncthreads();
  if (t < 32) invk[t] = rsqrtf(red[0][t] + red[1][t] + red[2][t] + red[3][t]);
  __syncthreads();
  const float iv = invk[k];
#pragma unroll
  for (int rep = 0; rep < 32; ++rep) {
    int c = rep * 8 + w * 2 + h;
    T[k][c] = (__bf16)(fv[rep] * iv);
  }
  __syncthreads();

  // KAF image: slot = cf*128 + krow*4 + lg, 16B each; fully coalesced writes
  {
    const int jt = kt >> 1, st = kt & 1;
    char* KAFp = (char*)KAF + ((size_t)b * 64 + jt) * 32768 + st * 16384;
#pragma unroll
    for (int pass = 0; pass < 4; ++pass) {
      int slot = pass * 256 + t;
      int cf   = slot >> 7;
      int krow = (slot >> 2) & 31;
      int lgi  = slot & 3;
      bf16x8 v = *(const bf16x8*)&T[krow][cf * 32 + lgi * 8];
      *(bf16x8*)(KAFp + slot * 16) = v;
    }
  }
  // KB image (plain [c][k] for direct coalesced global frag loads)
  {
    __bf16* KBp = KB + ((size_t)b * 128 + kt) * (256 * 32);
#pragma unroll
    for (int pass = 0; pass < 4; ++pass) {
      int c = pass * 64 + (t >> 2);
      int v = t & 3;
      bf16x8 o;
#pragma unroll
      for (int j = 0; j < 8; ++j) o[j] = T[v * 8 + j][c];
      *(bf16x8*)&KBp[c * 32 + v * 8] = o;
    }
  }
}

// ============================================================================
// Fused attention, producer/consumer, q=128/block, KT=64 fat phases.
// Grid (8 batch, 32 q-tiles), 1024 threads = 16 waves, 1 block/CU.
//   waves 0-7  (producer): (kh = w>>2, qh = w&3): A-frags from L1/L2 regs,
//                          32k x 32q GEMM1, softmax, P -> LDS
//   waves 8-15 (consumer): cq = w-8: c0 = (cq>>1)*64, q-half = (cq&1)*64
// LDS: P dbuf 32KB (P[128 q][64 k] bf16, 128B rows of 8 16B-units (8 k each),
//   unit u stored at u^(q&7)) + lE[2][128]. 66 lgkm barriers per role.
// ============================================================================
__global__ __launch_bounds__(1024, 4)
void ca_attn11(const float* __restrict__ F, const __bf16* __restrict__ KAF,
               const __bf16* __restrict__ KB, float* __restrict__ Out) {
  __shared__ __align__(16) char Pl[2][16384];
  __shared__ float lE[256];

  const int tid  = threadIdx.x;
  const int lane = tid & 63;
  const int w    = tid >> 6;            // 0..15
  const int lq   = lane & 15;
  const int lg   = lane >> 4;
  const int b    = blockIdx.x;          // batch fastest -> one batch per XCD
  const int q0   = blockIdx.y * 128;

  const char* KFb = (const char*)KAF + (size_t)b * (size_t)NPIX * CH * 2;
  const char* KBb = (const char*)KB + (size_t)b * (size_t)NPIX * CH * 2;

  if (w < 8) {
    // =================== producer: GEMM1 + softmax ========================
    const int kh = w >> 2, qh = w & 3;
    const int qA = q0 + qh * 32 + lq;
    const int qB = qA + 16;
    const float* __restrict__ Fb = F + (size_t)b * CH * NPIX;

    // Q fragments (pre-scaled by L2E) + squared norms for the fixed shift
    bf16x8 qfA[8], qfB[8];
    float ssA = 0.f, ssB = 0.f;
#pragma unroll
    for (int cf = 0; cf < 8; ++cf) {
#pragma unroll
      for (int j = 0; j < 8; ++j) {
        int c = cf * 32 + lg * 8 + j;
        float va = Fb[(size_t)c * NPIX + qA];
        float vb = Fb[(size_t)c * NPIX + qB];
        qfA[cf][j] = (__bf16)(va * L2E);
        qfB[cf][j] = (__bf16)(vb * L2E);
        ssA = fmaf(va, va, ssA);
        ssB = fmaf(vb, vb, ssB);
      }
    }
    ssA += __shfl_xor(ssA, 16, 64); ssA += __shfl_xor(ssA, 32, 64);
    ssB += __shfl_xor(ssB, 16, 64); ssB += __shfl_xor(ssB, 32, 64);
    // m_q = ||F_q||: provable max of S[:,q] (K rows unit-norm), exact shift.
    const float mqA = sqrtf(ssA) * L2E, mqB = sqrtf(ssB) * L2E;

    float lA = 0.f, lB = 0.f;
    const int ksw = lq & 7;
    // per-lane offset within a 1KB fragment group: row lq (64B), sub lg (16B)
    const char* abase0 = KFb + kh * 1024 + lq * 64 + lg * 16;
    // P write: row q (128B), unit u = st*4 + kh*2 + (lg>>1), u ^= (q&7)=lq&7,
    // + (lg&1)*8 bytes within unit.  (k = u*8 + (lg&1)*4 + r)
    const int pwRowA = (qh * 32 + lq) * 128;
    const int pwRowB = pwRowA + 16 * 128;
    const int puBase = kh * 2 + (lg >> 1);
    const int pwSub  = ((lg & 1) << 3);
    const int u0 = (puBase ^ ksw) << 4;          // sub-tile 0 unit offset
    const int u1 = ((4 + puBase) ^ ksw) << 4;    // sub-tile 1 unit offset

    barrier_lgkm();                                  // #1

    const f32x4 zero = {0.f, 0.f, 0.f, 0.f};
    for (int i = 0; i < 64; ++i) {
      const int cb = i & 1;
      const char* ab = abase0 + (size_t)i * 32768;

      // GEMM1: 4 independent 8-deep chains; A-frags straight from L1/L2
      f32x4 s00 = zero, s01 = zero, s10 = zero, s11 = zero;
      __builtin_amdgcn_s_setprio(1);
#pragma unroll
      for (int cf = 0; cf < 8; ++cf) {
        bf16x8 a0 = *(const bf16x8*)(ab + cf * 2048);            // sub-tile 0
        bf16x8 a1 = *(const bf16x8*)(ab + 16384 + cf * 2048);    // sub-tile 1
        s00 = __builtin_amdgcn_mfma_f32_16x16x32_bf16(a0, qfA[cf], s00, 0, 0, 0);
        s01 = __builtin_amdgcn_mfma_f32_16x16x32_bf16(a0, qfB[cf], s01, 0, 0, 0);
        s10 = __builtin_amdgcn_mfma_f32_16x16x32_bf16(a1, qfA[cf], s10, 0, 0, 0);
        s11 = __builtin_amdgcn_mfma_f32_16x16x32_bf16(a1, qfB[cf], s11, 0, 0, 0);
      }
      __builtin_amdgcn_s_setprio(0);

      // softmax numerators (fixed shift), write P
      char* pb = Pl[cb];
      bf16x4 pv00, pv01, pv10, pv11;
#pragma unroll
      for (int r = 0; r < 4; ++r) {
        float p00 = __builtin_amdgcn_exp2f(s00[r] - mqA);
        float p01 = __builtin_amdgcn_exp2f(s01[r] - mqB);
        float p10 = __builtin_amdgcn_exp2f(s10[r] - mqA);
        float p11 = __builtin_amdgcn_exp2f(s11[r] - mqB);
        lA += p00 + p10; lB += p01 + p11;
        pv00[r] = (__bf16)p00; pv01[r] = (__bf16)p01;
        pv10[r] = (__bf16)p10; pv11[r] = (__bf16)p11;
      }
      *(bf16x4*)(pb + pwRowA + u0 + pwSub) = pv00;
      *(bf16x4*)(pb + pwRowB + u0 + pwSub) = pv01;
      *(bf16x4*)(pb + pwRowA + u1 + pwSub) = pv10;
      *(bf16x4*)(pb + pwRowB + u1 + pwSub) = pv11;

      barrier_lgkm();                                // #i+2
    }

    // final softmax denominators -> lE
    lA += __shfl_xor(lA, 16, 64); lA += __shfl_xor(lA, 32, 64);
    lB += __shfl_xor(lB, 16, 64); lB += __shfl_xor(lB, 32, 64);
    if (lg == 0) lE[kh * 128 + qh * 32 + lq] = lA;
    if (lg == 1) lE[kh * 128 + qh * 32 + 16 + lq] = lB;
    barrier_lgkm();                                  // #66

  } else {
    // =================== consumer: GEMM2 ==================================
    const int cq  = w - 8;
    const int c0  = (cq >> 1) * 64;
    const int qh2 = cq & 1;                          // q-half (64 q)
    const size_t fragBase = (size_t)(c0 + lq) * 64 + (size_t)lg * 16;
    // pf read: row = qh2*64 + qf*16 + lq, unit u = kf*4+lg, u ^= (lq&7)
    const int prRow = (qh2 * 64 + lq) * 128;
    const int prU0  = ((0 * 4 + lg) ^ (lq & 7)) << 4;   // kf=0
    const int prU1  = ((1 * 4 + lg) ^ (lq & 7)) << 4;   // kf=1

    const f32x4 zero = {0.f, 0.f, 0.f, 0.f};
    f32x4 oacc[4][4];
#pragma unroll
    for (int i = 0; i < 4; ++i)
#pragma unroll
      for (int j = 0; j < 4; ++j) oacc[i][j] = zero;

    barrier_lgkm();                                  // #1

    for (int jt = 0; jt < 64; ++jt) {
      // issue KB frag loads for tile jt (full phase to land across barrier)
      const char* kb0 = KBb + (size_t)(2 * jt) * 16384 + fragBase;
      const char* kb1 = kb0 + 16384;
      bf16x8 k00 = *(const bf16x8*)(kb0);
      bf16x8 k01 = *(const bf16x8*)(kb0 + 1024);
      bf16x8 k02 = *(const bf16x8*)(kb0 + 2048);
      bf16x8 k03 = *(const bf16x8*)(kb0 + 3072);
      bf16x8 k10 = *(const bf16x8*)(kb1);
      bf16x8 k11 = *(const bf16x8*)(kb1 + 1024);
      bf16x8 k12 = *(const bf16x8*)(kb1 + 2048);
      bf16x8 k13 = *(const bf16x8*)(kb1 + 3072);

      barrier_lgkm();                                // #jt+2: P(jt) ready

      const char* pb = Pl[jt & 1];
      __builtin_amdgcn_s_setprio(1);
#pragma unroll
      for (int qf = 0; qf < 4; ++qf) {
        bf16x8 pf0 = *(const bf16x8*)(pb + prRow + qf * 2048 + prU0);
        oacc[0][qf] = __builtin_amdgcn_mfma_f32_16x16x32_bf16(k00, pf0, oacc[0][qf], 0, 0, 0);
        oacc[1][qf] = __builtin_amdgcn_mfma_f32_16x16x32_bf16(k01, pf0, oacc[1][qf], 0, 0, 0);
        oacc[2][qf] = __builtin_amdgcn_mfma_f32_16x16x32_bf16(k02, pf0, oacc[2][qf], 0, 0, 0);
        oacc[3][qf] = __builtin_amdgcn_mfma_f32_16x16x32_bf16(k03, pf0, oacc[3][qf], 0, 0, 0);
      }
#pragma unroll
      for (int qf = 0; qf < 4; ++qf) {
        bf16x8 pf1 = *(const bf16x8*)(pb + prRow + qf * 2048 + prU1);
        oacc[0][qf] = __builtin_amdgcn_mfma_f32_16x16x32_bf16(k10, pf1, oacc[0][qf], 0, 0, 0);
        oacc[1][qf] = __builtin_amdgcn_mfma_f32_16x16x32_bf16(k11, pf1, oacc[1][qf], 0, 0, 0);
        oacc[2][qf] = __builtin_amdgcn_mfma_f32_16x16x32_bf16(k12, pf1, oacc[2][qf], 0, 0, 0);
        oacc[3][qf] = __builtin_amdgcn_mfma_f32_16x16x32_bf16(k13, pf1, oacc[3][qf], 0, 0, 0);
      }
      __builtin_amdgcn_s_setprio(0);
    }

    barrier_lgkm();                                  // #66: lE published

    // epilogue: normalize and store
    const int qb = qh2 * 64;
    float rl0 = 1.0f / (lE[qb + 0 * 16 + lq] + lE[128 + qb + 0 * 16 + lq]);
    float rl1 = 1.0f / (lE[qb + 1 * 16 + lq] + lE[128 + qb + 1 * 16 + lq]);
    float rl2 = 1.0f / (lE[qb + 2 * 16 + lq] + lE[128 + qb + 2 * 16 + lq]);
    float rl3 = 1.0f / (lE[qb + 3 * 16 + lq] + lE[128 + qb + 3 * 16 + lq]);
    float* __restrict__ Ob = Out + (size_t)b * CH * NPIX;
#pragma unroll
    for (int ct = 0; ct < 4; ++ct) {
#pragma unroll
      for (int r = 0; r < 4; ++r) {
        const int c = c0 + ct * 16 + lg * 4 + r;
        float* orow = Ob + (size_t)c * NPIX + q0 + qb;
        orow[0 * 16 + lq] = oacc[ct][0][r] * rl0;
        orow[1 * 16 + lq] = oacc[ct][1][r] * rl1;
        orow[2 * 16 + lq] = oacc[ct][2][r] * rl2;
        orow[3 * 16 + lq] = oacc[ct][3][r] * rl3;
      }
    }
  }
}

// ============================================================================
extern "C" void kernel_launch(void* const* d_in, const int* in_sizes, int n_in,
                              void* d_out, int out_size, void* d_ws, size_t ws_size,
                              hipStream_t stream) {
  const float* F = (const float*)d_in[0];
  float* out = (float*)d_out;
  const size_t imgElems = (size_t)BATCH * NPIX * CH;   // 8.4M bf16 per image

  __bf16* KAFi = (__bf16*)d_ws;           // ws >= 33.6 MB (verified rounds 2-10)
  __bf16* KBi  = KAFi + imgElems;
  ca_prep<<<dim3(BATCH, 128), 256, 0, stream>>>(F, KAFi, KBi);
  ca_attn11<<<dim3(BATCH, 32), 1024, 0, stream>>>(F, KAFi, KBi, out);
}

// Round 13
// 127.710 us; speedup vs baseline: 1.8841x; 1.8841x over previous
//
#include <hip/hip_runtime.h>
#include <hip/hip_fp8.h>

// ContextualAttention: out[b,c,p] = sum_k K[b,k,c] * softmax_k( K[b,:,:] @ F[b,:,p] )
// K = rowwise-normalized (F^T + eps). Flash-style fusion, f32 accum.
// Round 12: r9 skeleton (q=128/block, 16 waves, producer/consumer, KT=64) with
//   the GEMM1 path in fp8 e4m3: KA image + Q frags fp8 (mfma_..._fp8_fp8,
//   same rate as bf16 but half the LDS/DMA bytes). GEMM2/P/out stay bf16/f32.
//   KA fp8 rows: 256B, 8B-unit u stored at u^(krow&15) -> conflict-free b64.

#define BATCH 8
#define CH 256
#define NPIX 4096
#define EPSV 1e-7f
#define L2E 1.4426950408889634f

using bf16x8 = __attribute__((ext_vector_type(8))) __bf16;
using bf16x4 = __attribute__((ext_vector_type(4))) __bf16;
using f32x4  = __attribute__((ext_vector_type(4))) float;

__device__ __forceinline__ void gload16(const void* g, void* l) {
  __builtin_amdgcn_global_load_lds(
      (const __attribute__((address_space(1))) unsigned int*)g,
      (__attribute__((address_space(3))) unsigned int*)l, 16, 0, 0);
}

// producer barrier: full drain (its global_load_lds results are read by OTHER
// producer waves next phase; P writes must be visible).
__device__ __forceinline__ void barrier_full() {
  asm volatile("s_waitcnt vmcnt(0) lgkmcnt(0)\n"
               "s_barrier" ::: "memory");
}
// consumer barrier: LDS-only drain; its global->reg prefetch stays in flight.
__device__ __forceinline__ void barrier_lgkm() {
  asm volatile("s_waitcnt lgkmcnt(0)\n"
               "s_barrier" ::: "memory");
}

__device__ __forceinline__ unsigned char to_fp8(float f) {
  return __hip_cvt_float_to_fp8(f, __HIP_SATFINITE, __HIP_E4M3);
}

// ============================================================================
// Prep: per (batch, 32-key tile): inv-norms, normalized K, two images:
//   KA[b][kt][32 k][256 c] fp8: 256B rows, 8B-unit u at u^(k&15)  (GEMM1 LDS)
//   KB[b][kt][256 c][32 k] bf16: plain layout                     (GEMM2 L2)
// ============================================================================
__global__ __launch_bounds__(256)
void ca_prep(const float* __restrict__ F, unsigned char* __restrict__ KA,
             __bf16* __restrict__ KB) {
  const int b   = blockIdx.x;
  const int kt  = blockIdx.y;          // 128 tiles of 32 keys
  const int kt0 = kt * 32;
  const int t   = threadIdx.x;
  const int k   = t & 31;
  const int h   = (t >> 5) & 1;
  const int w   = t >> 6;

  const float* __restrict__ Fb = F + (size_t)b * CH * NPIX;

  __shared__ float red[4][32];
  __shared__ float invk[32];
  __shared__ __align__(16) __bf16 T[32][264];   // +8 pad (528B rows)

  float fv[32];
  float ss = 0.f;
#pragma unroll
  for (int rep = 0; rep < 32; ++rep) {
    int c = rep * 8 + w * 2 + h;
    float v = Fb[(size_t)c * NPIX + kt0 + k] + EPSV;
    fv[rep] = v;
    ss = fmaf(v, v, ss);
  }
  ss += __shfl_xor(ss, 32, 64);
  if ((t & 32) == 0) red[w][k] = ss;
  __syncthreads();
  if (t < 32) invk[t] = rsqrtf(red[0][t] + red[1][t] + red[2][t] + red[3][t]);
  __syncthreads();
  const float iv = invk[k];
#pragma unroll
  for (int rep = 0; rep < 32; ++rep) {
    int c = rep * 8 + w * 2 + h;
    T[k][c] = (__bf16)(fv[rep] * iv);
  }
  __syncthreads();

  // KA image (fp8, swizzled): slot = (krow, u); store at krow*256 + (u^(krow&15))*8
  {
    char* KAp = (char*)KA + ((size_t)b * 128 + kt) * (32 * 256);
#pragma unroll
    for (int pass = 0; pass < 4; ++pass) {
      int slot = pass * 256 + t;
      int krow = slot >> 5;
      int u    = slot & 31;
      bf16x8 v = *(const bf16x8*)&T[krow][u * 8];
      unsigned char pk[8];
#pragma unroll
      for (int j = 0; j < 8; ++j) pk[j] = to_fp8((float)v[j]);
      *(long*)(KAp + krow * 256 + ((u ^ (krow & 15)) * 8)) = *(const long*)pk;
    }
  }
  // KB image (plain [c][k] bf16 for direct coalesced global frag loads)
  {
    __bf16* KBp = KB + ((size_t)b * 128 + kt) * (256 * 32);
#pragma unroll
    for (int pass = 0; pass < 4; ++pass) {
      int c = pass * 64 + (t >> 2);
      int v = t & 3;
      bf16x8 o;
#pragma unroll
      for (int j = 0; j < 8; ++j) o[j] = T[v * 8 + j][c];
      *(bf16x8*)&KBp[c * 32 + v * 8] = o;
    }
  }
}

// ============================================================================
// Fused attention, producer/consumer, q=128/block, KT=64 fat phases.
// Grid (8 batch, 32 q-tiles), 1024 threads = 16 waves, 1 block/CU.
//   waves 0-7  (producer): (kh = w>>2, qh = w&3) -> 32k x 32q fp8 GEMM1 + softmax
//   waves 8-15 (consumer): cq = w-8: c0 = (cq>>1)*64, q-half = (cq&1)*64 (bf16)
// smem (64KB):
//   [0,32K)  KA dbuf (fp8): buf cb at cb*16384, two 8KB sub-tiles (32k x 256c,
//            256B rows, 8B-unit u at u^(k&15))
//   [32K,64K) P dbuf: buf pb at 32K + pb*16384: P[128 q][64 k] bf16, 128B rows
//            of 8 16B-units (8 k each), unit u stored at u^(q&7)
//   lE[2][128] floats aliased at smem+0 (KA buf0 dead in final phase).
// 66 barriers per role.
// ============================================================================
__global__ __launch_bounds__(1024, 4)
void ca_attn12(const float* __restrict__ F, const unsigned char* __restrict__ KA,
               const __bf16* __restrict__ KB, float* __restrict__ Out) {
  __shared__ __align__(16) char smem[65536];

  const int tid  = threadIdx.x;
  const int lane = tid & 63;
  const int w    = tid >> 6;            // 0..15
  const int lq   = lane & 15;
  const int lg   = lane >> 4;
  const int b    = blockIdx.x;          // batch fastest -> one batch per XCD
  const int q0   = blockIdx.y * 128;

  const char* KAb = (const char*)KA + (size_t)b * (size_t)NPIX * CH;
  const char* KBb = (const char*)KB + (size_t)b * (size_t)NPIX * CH * 2;
  char* PlB = smem + 32768;

  if (w < 8) {
    // =================== producer: fp8 GEMM1 + softmax ====================
    const int kh = w >> 2, qh = w & 3;
    const int qA = q0 + qh * 32 + lq;
    const int qB = qA + 16;
    const float* __restrict__ Fb = F + (size_t)b * CH * NPIX;
    const int wo = w * 2048;            // this wave's 2KB slice of a 16KB tile

    // stage tile 0 -> buf 0 (overlaps Q loads below)
#pragma unroll
    for (int j = 0; j < 2; ++j)
      gload16(KAb + wo + j * 1024 + lane * 16, smem + wo + j * 1024);

    // Q fragments (fp8, pre-scaled by L2E) + squared norms for the fixed shift
    long qpA[8], qpB[8];
    float ssA = 0.f, ssB = 0.f;
#pragma unroll
    for (int cf = 0; cf < 8; ++cf) {
      unsigned char pa[8], pb8[8];
#pragma unroll
      for (int j = 0; j < 8; ++j) {
        int c = cf * 32 + lg * 8 + j;
        float va = Fb[(size_t)c * NPIX + qA];
        float vb = Fb[(size_t)c * NPIX + qB];
        pa[j]  = to_fp8(va * L2E);
        pb8[j] = to_fp8(vb * L2E);
        ssA = fmaf(va, va, ssA);
        ssB = fmaf(vb, vb, ssB);
      }
      qpA[cf] = *(const long*)pa;
      qpB[cf] = *(const long*)pb8;
    }
    ssA += __shfl_xor(ssA, 16, 64); ssA += __shfl_xor(ssA, 32, 64);
    ssB += __shfl_xor(ssB, 16, 64); ssB += __shfl_xor(ssB, 32, 64);
    // m_q = ||F_q||: provable max of S[:,q] (K rows unit-norm), exact shift.
    const float mqA = sqrtf(ssA) * L2E, mqB = sqrtf(ssB) * L2E;

    float lA = 0.f, lB = 0.f;
    const int krow = kh * 16 + lq;      // A row within each 32k sub-tile
    const int rowByte = krow * 256;     // fp8 row = 256B; swizzle key = lq
    // P write: row q (128B), unit u = st*4 + kh*2 + (lg>>1), u ^= (q&7)=lq&7,
    // + (lg&1)*8 bytes within unit.  (k = u*8 + (lg&1)*4 + r)
    const int ksw = lq & 7;
    const int pwRowA = (qh * 32 + lq) * 128;
    const int pwRowB = pwRowA + 16 * 128;
    const int puBase = kh * 2 + (lg >> 1);
    const int pwSub  = ((lg & 1) << 3);
    const int u0 = (puBase ^ ksw) << 4;          // sub-tile 0 unit offset
    const int u1 = ((4 + puBase) ^ ksw) << 4;    // sub-tile 1 unit offset

    barrier_full();                                  // #1: tile 0 landed

    const f32x4 zero = {0.f, 0.f, 0.f, 0.f};
    for (int i = 0; i < 64; ++i) {
      const int cb = i & 1;
      if (i < 63) {                                  // stage tile i+1
        const char* s = KAb + (size_t)(i + 1) * 16384;
        char* d = smem + (cb ^ 1) * 16384;
#pragma unroll
        for (int j = 0; j < 2; ++j)
          gload16(s + wo + j * 1024 + lane * 16, d + wo + j * 1024);
      }

      // GEMM1 (fp8): 4 independent 8-deep chains (2 sub-tiles x 2 q-frags)
      const char* ab0 = smem + cb * 16384 + rowByte;          // sub-tile 0
      const char* ab1 = ab0 + 8192;                           // sub-tile 1
      f32x4 s00 = zero, s01 = zero, s10 = zero, s11 = zero;
      __builtin_amdgcn_s_setprio(1);
#pragma unroll
      for (int cf = 0; cf < 8; ++cf) {
        const int uo = ((((cf << 2) | lg) ^ lq) << 3);
        long a0 = *(const long*)(ab0 + uo);
        long a1 = *(const long*)(ab1 + uo);
        s00 = __builtin_amdgcn_mfma_f32_16x16x32_fp8_fp8(a0, qpA[cf], s00, 0, 0, 0);
        s01 = __builtin_amdgcn_mfma_f32_16x16x32_fp8_fp8(a0, qpB[cf], s01, 0, 0, 0);
        s10 = __builtin_amdgcn_mfma_f32_16x16x32_fp8_fp8(a1, qpA[cf], s10, 0, 0, 0);
        s11 = __builtin_amdgcn_mfma_f32_16x16x32_fp8_fp8(a1, qpB[cf], s11, 0, 0, 0);
      }
      __builtin_amdgcn_s_setprio(0);

      // softmax numerators (fixed shift), write P (bf16)
      char* pb = PlB + cb * 16384;
      bf16x4 pv00, pv01, pv10, pv11;
#pragma unroll
      for (int r = 0; r < 4; ++r) {
        float p00 = __builtin_amdgcn_exp2f(s00[r] - mqA);
        float p01 = __builtin_amdgcn_exp2f(s01[r] - mqB);
        float p10 = __builtin_amdgcn_exp2f(s10[r] - mqA);
        float p11 = __builtin_amdgcn_exp2f(s11[r] - mqB);
        lA += p00 + p10; lB += p01 + p11;
        pv00[r] = (__bf16)p00; pv01[r] = (__bf16)p01;
        pv10[r] = (__bf16)p10; pv11[r] = (__bf16)p11;
      }
      *(bf16x4*)(pb + pwRowA + u0 + pwSub) = pv00;
      *(bf16x4*)(pb + pwRowB + u0 + pwSub) = pv01;
      *(bf16x4*)(pb + pwRowA + u1 + pwSub) = pv10;
      *(bf16x4*)(pb + pwRowB + u1 + pwSub) = pv11;

      barrier_full();                                // #i+2
    }

    // final softmax denominators -> lE (aliased at smem+0; KA buf0 is dead)
    lA += __shfl_xor(lA, 16, 64); lA += __shfl_xor(lA, 32, 64);
    lB += __shfl_xor(lB, 16, 64); lB += __shfl_xor(lB, 32, 64);
    float* lE = (float*)smem;
    if (lg == 0) lE[kh * 128 + qh * 32 + lq] = lA;
    if (lg == 1) lE[kh * 128 + qh * 32 + 16 + lq] = lB;
    barrier_full();                                  // #66

  } else {
    // =================== consumer: GEMM2 (bf16) ===========================
    const int cq  = w - 8;
    const int c0  = (cq >> 1) * 64;
    const int qh2 = cq & 1;                          // q-half (64 q)
    const size_t fragBase = (size_t)(c0 + lq) * 64 + (size_t)lg * 16;
    // pf read: row = qh2*64 + qf*16 + lq, unit u = kf*4+lg, u ^= (lq&7)
    const int prRow = (qh2 * 64 + lq) * 128;
    const int prU0  = ((0 * 4 + lg) ^ (lq & 7)) << 4;   // kf=0
    const int prU1  = ((1 * 4 + lg) ^ (lq & 7)) << 4;   // kf=1

    const f32x4 zero = {0.f, 0.f, 0.f, 0.f};
    f32x4 oacc[4][4];
#pragma unroll
    for (int i = 0; i < 4; ++i)
#pragma unroll
      for (int j = 0; j < 4; ++j) oacc[i][j] = zero;

    barrier_lgkm();                                  // #1

    for (int jt = 0; jt < 64; ++jt) {
      // issue KB frag loads for tile jt (full phase to land across barrier)
      const char* kb0 = KBb + (size_t)(2 * jt) * 16384 + fragBase;
      const char* kb1 = kb0 + 16384;
      bf16x8 k00 = *(const bf16x8*)(kb0);
      bf16x8 k01 = *(const bf16x8*)(kb0 + 1024);
      bf16x8 k02 = *(const bf16x8*)(kb0 + 2048);
      bf16x8 k03 = *(const bf16x8*)(kb0 + 3072);
      bf16x8 k10 = *(const bf16x8*)(kb1);
      bf16x8 k11 = *(const bf16x8*)(kb1 + 1024);
      bf16x8 k12 = *(const bf16x8*)(kb1 + 2048);
      bf16x8 k13 = *(const bf16x8*)(kb1 + 3072);

      barrier_lgkm();                                // #jt+2: P(jt) ready

      const char* pb = PlB + (jt & 1) * 16384;
      __builtin_amdgcn_s_setprio(1);
#pragma unroll
      for (int qf = 0; qf < 4; ++qf) {
        bf16x8 pf0 = *(const bf16x8*)(pb + prRow + qf * 2048 + prU0);
        oacc[0][qf] = __builtin_amdgcn_mfma_f32_16x16x32_bf16(k00, pf0, oacc[0][qf], 0, 0, 0);
        oacc[1][qf] = __builtin_amdgcn_mfma_f32_16x16x32_bf16(k01, pf0, oacc[1][qf], 0, 0, 0);
        oacc[2][qf] = __builtin_amdgcn_mfma_f32_16x16x32_bf16(k02, pf0, oacc[2][qf], 0, 0, 0);
        oacc[3][qf] = __builtin_amdgcn_mfma_f32_16x16x32_bf16(k03, pf0, oacc[3][qf], 0, 0, 0);
      }
#pragma unroll
      for (int qf = 0; qf < 4; ++qf) {
        bf16x8 pf1 = *(const bf16x8*)(pb + prRow + qf * 2048 + prU1);
        oacc[0][qf] = __builtin_amdgcn_mfma_f32_16x16x32_bf16(k10, pf1, oacc[0][qf], 0, 0, 0);
        oacc[1][qf] = __builtin_amdgcn_mfma_f32_16x16x32_bf16(k11, pf1, oacc[1][qf], 0, 0, 0);
        oacc[2][qf] = __builtin_amdgcn_mfma_f32_16x16x32_bf16(k12, pf1, oacc[2][qf], 0, 0, 0);
        oacc[3][qf] = __builtin_amdgcn_mfma_f32_16x16x32_bf16(k13, pf1, oacc[3][qf], 0, 0, 0);
      }
      __builtin_amdgcn_s_setprio(0);
    }

    barrier_lgkm();                                  // #66: lE published

    // epilogue: normalize and store
    const float* lE = (const float*)smem;
    const int qb = qh2 * 64;
    float rl0 = 1.0f / (lE[qb + 0 * 16 + lq] + lE[128 + qb + 0 * 16 + lq]);
    float rl1 = 1.0f / (lE[qb + 1 * 16 + lq] + lE[128 + qb + 1 * 16 + lq]);
    float rl2 = 1.0f / (lE[qb + 2 * 16 + lq] + lE[128 + qb + 2 * 16 + lq]);
    float rl3 = 1.0f / (lE[qb + 3 * 16 + lq] + lE[128 + qb + 3 * 16 + lq]);
    float* __restrict__ Ob = Out + (size_t)b * CH * NPIX;
#pragma unroll
    for (int ct = 0; ct < 4; ++ct) {
#pragma unroll
      for (int r = 0; r < 4; ++r) {
        const int c = c0 + ct * 16 + lg * 4 + r;
        float* orow = Ob + (size_t)c * NPIX + q0 + qb;
        orow[0 * 16 + lq] = oacc[ct][0][r] * rl0;
        orow[1 * 16 + lq] = oacc[ct][1][r] * rl1;
        orow[2 * 16 + lq] = oacc[ct][2][r] * rl2;
        orow[3 * 16 + lq] = oacc[ct][3][r] * rl3;
      }
    }
  }
}

// ============================================================================
extern "C" void kernel_launch(void* const* d_in, const int* in_sizes, int n_in,
                              void* d_out, int out_size, void* d_ws, size_t ws_size,
                              hipStream_t stream) {
  const float* F = (const float*)d_in[0];
  float* out = (float*)d_out;
  const size_t imgBytes = (size_t)BATCH * NPIX * CH;   // fp8 image = 8.4 MB

  unsigned char* KAi = (unsigned char*)d_ws;
  __bf16* KBi = (__bf16*)((char*)d_ws + imgBytes);     // bf16 image = 16.8 MB
  ca_prep<<<dim3(BATCH, 128), 256, 0, stream>>>(F, KAi, KBi);
  ca_attn12<<<dim3(BATCH, 32), 1024, 0, stream>>>(F, KAi, KBi, out);
}

// Round 14
// 124.920 us; speedup vs baseline: 1.9261x; 1.0223x over previous
//
#include <hip/hip_runtime.h>
#include <hip/hip_fp8.h>

// ContextualAttention: out[b,c,p] = sum_k K[b,k,c] * softmax_k( K[b,:,:] @ F[b,:,p] )
// K = rowwise-normalized (F^T + eps). Flash-style fusion, f32 accum.
// Round 13: KT=128 fat phases (32 phases, 34 barriers). fp8 GEMM1 (r12),
//   bf16 GEMM2. LDS 128KB: KA fp8 dbuf 64K + P dbuf 64K, lE aliased.
//   Producer: 8 indep 8-deep fp8 chains. Consumer: kb reg set reused
//   mid-phase to hold VGPR <=128 at 4 waves/SIMD.

#define BATCH 8
#define CH 256
#define NPIX 4096
#define EPSV 1e-7f
#define L2E 1.4426950408889634f

using bf16x8 = __attribute__((ext_vector_type(8))) __bf16;
using bf16x4 = __attribute__((ext_vector_type(4))) __bf16;
using f32x4  = __attribute__((ext_vector_type(4))) float;

__device__ __forceinline__ void gload16(const void* g, void* l) {
  __builtin_amdgcn_global_load_lds(
      (const __attribute__((address_space(1))) unsigned int*)g,
      (__attribute__((address_space(3))) unsigned int*)l, 16, 0, 0);
}

// producer barrier: full drain (its global_load_lds results are read by OTHER
// producer waves next phase; P writes must be visible).
__device__ __forceinline__ void barrier_full() {
  asm volatile("s_waitcnt vmcnt(0) lgkmcnt(0)\n"
               "s_barrier" ::: "memory");
}
// consumer barrier: LDS-only drain; its global->reg prefetch stays in flight.
__device__ __forceinline__ void barrier_lgkm() {
  asm volatile("s_waitcnt lgkmcnt(0)\n"
               "s_barrier" ::: "memory");
}

__device__ __forceinline__ unsigned char to_fp8(float f) {
  return __hip_cvt_float_to_fp8(f, __HIP_SATFINITE, __HIP_E4M3);
}

// ============================================================================
// Prep (unchanged from r12): per (batch, 32-key tile):
//   KA[b][kt][32 k][256 c] fp8: 256B rows, 8B-unit u at u^(k&15)  (GEMM1 LDS)
//   KB[b][kt][256 c][32 k] bf16: plain layout                     (GEMM2 L2)
// ============================================================================
__global__ __launch_bounds__(256)
void ca_prep(const float* __restrict__ F, unsigned char* __restrict__ KA,
             __bf16* __restrict__ KB) {
  const int b   = blockIdx.x;
  const int kt  = blockIdx.y;          // 128 tiles of 32 keys
  const int kt0 = kt * 32;
  const int t   = threadIdx.x;
  const int k   = t & 31;
  const int h   = (t >> 5) & 1;
  const int w   = t >> 6;

  const float* __restrict__ Fb = F + (size_t)b * CH * NPIX;

  __shared__ float red[4][32];
  __shared__ float invk[32];
  __shared__ __align__(16) __bf16 T[32][264];   // +8 pad (528B rows)

  float fv[32];
  float ss = 0.f;
#pragma unroll
  for (int rep = 0; rep < 32; ++rep) {
    int c = rep * 8 + w * 2 + h;
    float v = Fb[(size_t)c * NPIX + kt0 + k] + EPSV;
    fv[rep] = v;
    ss = fmaf(v, v, ss);
  }
  ss += __shfl_xor(ss, 32, 64);
  if ((t & 32) == 0) red[w][k] = ss;
  __syncthreads();
  if (t < 32) invk[t] = rsqrtf(red[0][t] + red[1][t] + red[2][t] + red[3][t]);
  __syncthreads();
  const float iv = invk[k];
#pragma unroll
  for (int rep = 0; rep < 32; ++rep) {
    int c = rep * 8 + w * 2 + h;
    T[k][c] = (__bf16)(fv[rep] * iv);
  }
  __syncthreads();

  // KA image (fp8, swizzled)
  {
    char* KAp = (char*)KA + ((size_t)b * 128 + kt) * (32 * 256);
#pragma unroll
    for (int pass = 0; pass < 4; ++pass) {
      int slot = pass * 256 + t;
      int krow = slot >> 5;
      int u    = slot & 31;
      bf16x8 v = *(const bf16x8*)&T[krow][u * 8];
      unsigned char pk[8];
#pragma unroll
      for (int j = 0; j < 8; ++j) pk[j] = to_fp8((float)v[j]);
      *(long*)(KAp + krow * 256 + ((u ^ (krow & 15)) * 8)) = *(const long*)pk;
    }
  }
  // KB image (plain [c][k] bf16)
  {
    __bf16* KBp = KB + ((size_t)b * 128 + kt) * (256 * 32);
#pragma unroll
    for (int pass = 0; pass < 4; ++pass) {
      int c = pass * 64 + (t >> 2);
      int v = t & 3;
      bf16x8 o;
#pragma unroll
      for (int j = 0; j < 8; ++j) o[j] = T[v * 8 + j][c];
      *(bf16x8*)&KBp[c * 32 + v * 8] = o;
    }
  }
}

// ============================================================================
// Fused attention, producer/consumer, q=128/block, KT=128 fat phases.
// Grid (8 batch, 32 q-tiles), 1024 threads = 16 waves, 1 block/CU.
//   waves 0-7  (producer): (kh = w>>2, qh = w&3) -> 64k x 32q fp8 GEMM1/softmax
//   waves 8-15 (consumer): cq = w-8: c0 = (cq>>1)*64, q-half = (cq&1)*64 (bf16)
// smem (128KB):
//   [0,64K)   KA dbuf (fp8): buf cb at cb*32768 = 4 sub-tiles of 8KB
//             (32k x 256c, 256B rows, 8B-unit u at u^(k&15))
//   [64K,128K) P dbuf: buf pb at 64K + pb*32768: P[128 q][128 k] bf16,
//             256B rows of 16 16B-units (8 k each), unit u at u^(q&7)
//   lE[2][128] floats aliased at smem+0 (KA buf0 dead in final phase).
// 34 barriers per role.
// ============================================================================
__global__ __launch_bounds__(1024, 4)
void ca_attn13(const float* __restrict__ F, const unsigned char* __restrict__ KA,
               const __bf16* __restrict__ KB, float* __restrict__ Out) {
  __shared__ __align__(16) char smem[131072];

  const int tid  = threadIdx.x;
  const int lane = tid & 63;
  const int w    = tid >> 6;            // 0..15
  const int lq   = lane & 15;
  const int lg   = lane >> 4;
  const int b    = blockIdx.x;          // batch fastest -> one batch per XCD
  const int q0   = blockIdx.y * 128;

  const char* KAb = (const char*)KA + (size_t)b * (size_t)NPIX * CH;
  const char* KBb = (const char*)KB + (size_t)b * (size_t)NPIX * CH * 2;
  char* PlB = smem + 65536;

  if (w < 8) {
    // =================== producer: fp8 GEMM1 + softmax ====================
    const int kh = w >> 2, qh = w & 3;
    const int qA = q0 + qh * 32 + lq;
    const int qB = qA + 16;
    const float* __restrict__ Fb = F + (size_t)b * CH * NPIX;
    const int wo = w * 4096;            // this wave's 4KB slice of a 32KB tile

    // stage tile 0 -> buf 0 (overlaps Q loads below)
#pragma unroll
    for (int j = 0; j < 4; ++j)
      gload16(KAb + wo + j * 1024 + lane * 16, smem + wo + j * 1024);

    // Q fragments (fp8, pre-scaled by L2E) + squared norms for the fixed shift
    long qpA[8], qpB[8];
    float ssA = 0.f, ssB = 0.f;
#pragma unroll
    for (int cf = 0; cf < 8; ++cf) {
      unsigned char pa[8], pb8[8];
#pragma unroll
      for (int j = 0; j < 8; ++j) {
        int c = cf * 32 + lg * 8 + j;
        float va = Fb[(size_t)c * NPIX + qA];
        float vb = Fb[(size_t)c * NPIX + qB];
        pa[j]  = to_fp8(va * L2E);
        pb8[j] = to_fp8(vb * L2E);
        ssA = fmaf(va, va, ssA);
        ssB = fmaf(vb, vb, ssB);
      }
      qpA[cf] = *(const long*)pa;
      qpB[cf] = *(const long*)pb8;
    }
    ssA += __shfl_xor(ssA, 16, 64); ssA += __shfl_xor(ssA, 32, 64);
    ssB += __shfl_xor(ssB, 16, 64); ssB += __shfl_xor(ssB, 32, 64);
    // m_q = ||F_q||: provable max of S[:,q] (K rows unit-norm), exact shift.
    const float mqA = sqrtf(ssA) * L2E, mqB = sqrtf(ssB) * L2E;

    float lA = 0.f, lB = 0.f;
    // P write: row q (256B), unit u = kh*8 + ks*2 + (lg>>1), u ^= (q&7)=lq&7,
    // + (lg&1)*8 bytes within unit.  (k = u*8 + (lg&1)*4 + r)
    const int ksw = lq & 7;
    const int pwRowA = (qh * 32 + lq) * 256;
    const int pwRowB = pwRowA + 16 * 256;
    const int pwSub  = ((lg & 1) << 3);
    const int puBase = kh * 8 + (lg >> 1);

    barrier_full();                                  // #1: tile 0 landed

    const f32x4 zero = {0.f, 0.f, 0.f, 0.f};
    for (int i = 0; i < 32; ++i) {
      const int cb = i & 1;
      if (i < 31) {                                  // stage tile i+1
        const char* s = KAb + (size_t)(i + 1) * 32768;
        char* d = smem + (cb ^ 1) * 32768;
#pragma unroll
        for (int j = 0; j < 4; ++j)
          gload16(s + wo + j * 1024 + lane * 16, d + wo + j * 1024);
      }

      // GEMM1 (fp8): 8 independent 8-deep chains (4 k-frags x 2 q-frags)
      f32x4 acc[4][2];
#pragma unroll
      for (int ks = 0; ks < 4; ++ks) { acc[ks][0] = zero; acc[ks][1] = zero; }
      const char* tb = smem + cb * 32768 + kh * 16384;
      __builtin_amdgcn_s_setprio(1);
#pragma unroll
      for (int cf = 0; cf < 8; ++cf) {
        const int uo = ((((cf << 2) | lg) ^ lq) << 3);
#pragma unroll
        for (int ks = 0; ks < 4; ++ks) {
          const char* ap = tb + (ks >> 1) * 8192 + ((ks & 1) * 16 + lq) * 256 + uo;
          long a = *(const long*)ap;
          acc[ks][0] = __builtin_amdgcn_mfma_f32_16x16x32_fp8_fp8(a, qpA[cf], acc[ks][0], 0, 0, 0);
          acc[ks][1] = __builtin_amdgcn_mfma_f32_16x16x32_fp8_fp8(a, qpB[cf], acc[ks][1], 0, 0, 0);
        }
      }
      __builtin_amdgcn_s_setprio(0);

      // softmax numerators (fixed shift), write P (bf16)
      char* pb = PlB + cb * 32768;
#pragma unroll
      for (int ks = 0; ks < 4; ++ks) {
        bf16x4 pv0, pv1;
#pragma unroll
        for (int r = 0; r < 4; ++r) {
          float p0 = __builtin_amdgcn_exp2f(acc[ks][0][r] - mqA);
          float p1 = __builtin_amdgcn_exp2f(acc[ks][1][r] - mqB);
          lA += p0; lB += p1;
          pv0[r] = (__bf16)p0;
          pv1[r] = (__bf16)p1;
        }
        const int uo = (((puBase + ks * 2) ^ ksw) << 4) + pwSub;
        *(bf16x4*)(pb + pwRowA + uo) = pv0;
        *(bf16x4*)(pb + pwRowB + uo) = pv1;
      }

      barrier_full();                                // #i+2
    }

    // final softmax denominators -> lE (aliased at smem+0; KA buf0 is dead)
    lA += __shfl_xor(lA, 16, 64); lA += __shfl_xor(lA, 32, 64);
    lB += __shfl_xor(lB, 16, 64); lB += __shfl_xor(lB, 32, 64);
    float* lE = (float*)smem;
    if (lg == 0) lE[kh * 128 + qh * 32 + lq] = lA;
    if (lg == 1) lE[kh * 128 + qh * 32 + 16 + lq] = lB;
    barrier_full();                                  // #34

  } else {
    // =================== consumer: GEMM2 (bf16) ===========================
    const int cq  = w - 8;
    const int c0  = (cq >> 1) * 64;
    const int qh2 = cq & 1;                          // q-half (64 q)
    const size_t fragBase = (size_t)(c0 + lq) * 64 + (size_t)lg * 16;
    // pf read: row = qh2*64 + qf*16 + lq (256B rows), unit u = kc*4+lg,
    // u ^= (lq&7)
    const int prRow = (qh2 * 64 + lq) * 256;
    const int q7 = lq & 7;

    const f32x4 zero = {0.f, 0.f, 0.f, 0.f};
    f32x4 oacc[4][4];
#pragma unroll
    for (int i = 0; i < 4; ++i)
#pragma unroll
      for (int j = 0; j < 4; ++j) oacc[i][j] = zero;

    bf16x8 k00, k01, k02, k03, k10, k11, k12, k13;

    // load chunk-pair (kc, kc+1) of phase jt into the kb register set
#define LOADPAIR(JT, KC)                                                      \
  do {                                                                        \
    const char* base = KBb + ((size_t)(JT) * 4 + (KC)) * 16384 + fragBase;    \
    k00 = *(const bf16x8*)(base);                                             \
    k01 = *(const bf16x8*)(base + 1024);                                      \
    k02 = *(const bf16x8*)(base + 2048);                                      \
    k03 = *(const bf16x8*)(base + 3072);                                      \
    k10 = *(const bf16x8*)(base + 16384);                                     \
    k11 = *(const bf16x8*)(base + 16384 + 1024);                              \
    k12 = *(const bf16x8*)(base + 16384 + 2048);                              \
    k13 = *(const bf16x8*)(base + 16384 + 3072);                              \
  } while (0)

    // MFMAs for chunk-pair (kc, kc+1) against P buffer pb
#define MFMAPAIR(PB, KC)                                                      \
  do {                                                                        \
    const char* pb_ = (PB);                                                   \
    const int u0 = ((((KC) << 2) | lg) ^ q7) << 4;                            \
    const int u1 = (((((KC) + 1) << 2) | lg) ^ q7) << 4;                      \
    __builtin_amdgcn_s_setprio(1);                                            \
    _Pragma("unroll")                                                         \
    for (int qf = 0; qf < 4; ++qf) {                                          \
      bf16x8 pf = *(const bf16x8*)(pb_ + prRow + qf * 4096 + u0);             \
      oacc[0][qf] = __builtin_amdgcn_mfma_f32_16x16x32_bf16(k00, pf, oacc[0][qf], 0, 0, 0); \
      oacc[1][qf] = __builtin_amdgcn_mfma_f32_16x16x32_bf16(k01, pf, oacc[1][qf], 0, 0, 0); \
      oacc[2][qf] = __builtin_amdgcn_mfma_f32_16x16x32_bf16(k02, pf, oacc[2][qf], 0, 0, 0); \
      oacc[3][qf] = __builtin_amdgcn_mfma_f32_16x16x32_bf16(k03, pf, oacc[3][qf], 0, 0, 0); \
    }                                                                         \
    _Pragma("unroll")                                                         \
    for (int qf = 0; qf < 4; ++qf) {                                          \
      bf16x8 pf = *(const bf16x8*)(pb_ + prRow + qf * 4096 + u1);             \
      oacc[0][qf] = __builtin_amdgcn_mfma_f32_16x16x32_bf16(k10, pf, oacc[0][qf], 0, 0, 0); \
      oacc[1][qf] = __builtin_amdgcn_mfma_f32_16x16x32_bf16(k11, pf, oacc[1][qf], 0, 0, 0); \
      oacc[2][qf] = __builtin_amdgcn_mfma_f32_16x16x32_bf16(k12, pf, oacc[2][qf], 0, 0, 0); \
      oacc[3][qf] = __builtin_amdgcn_mfma_f32_16x16x32_bf16(k13, pf, oacc[3][qf], 0, 0, 0); \
    }                                                                         \
    __builtin_amdgcn_s_setprio(0);                                            \
  } while (0)

    barrier_lgkm();                                  // #1
    LOADPAIR(0, 0);                                  // chunks 0,1 of phase 0

    for (int jt = 0; jt < 32; ++jt) {
      barrier_lgkm();                                // #jt+2: P(jt) ready
      const char* pb = PlB + (jt & 1) * 32768;
      MFMAPAIR(pb, 0);                               // chunks 0,1
      LOADPAIR(jt, 2);                               // chunks 2,3 (reuse regs)
      MFMAPAIR(pb, 2);                               // chunks 2,3
      if (jt < 31) LOADPAIR(jt + 1, 0);              // next phase chunks 0,1
    }
#undef LOADPAIR
#undef MFMAPAIR

    barrier_lgkm();                                  // #34: lE published

    // epilogue: normalize and store
    const float* lE = (const float*)smem;
    const int qb = qh2 * 64;
    float rl0 = 1.0f / (lE[qb + 0 * 16 + lq] + lE[128 + qb + 0 * 16 + lq]);
    float rl1 = 1.0f / (lE[qb + 1 * 16 + lq] + lE[128 + qb + 1 * 16 + lq]);
    float rl2 = 1.0f / (lE[qb + 2 * 16 + lq] + lE[128 + qb + 2 * 16 + lq]);
    float rl3 = 1.0f / (lE[qb + 3 * 16 + lq] + lE[128 + qb + 3 * 16 + lq]);
    float* __restrict__ Ob = Out + (size_t)b * CH * NPIX;
#pragma unroll
    for (int ct = 0; ct < 4; ++ct) {
#pragma unroll
      for (int r = 0; r < 4; ++r) {
        const int c = c0 + ct * 16 + lg * 4 + r;
        float* orow = Ob + (size_t)c * NPIX + q0 + qb;
        orow[0 * 16 + lq] = oacc[ct][0][r] * rl0;
        orow[1 * 16 + lq] = oacc[ct][1][r] * rl1;
        orow[2 * 16 + lq] = oacc[ct][2][r] * rl2;
        orow[3 * 16 + lq] = oacc[ct][3][r] * rl3;
      }
    }
  }
}

// ============================================================================
extern "C" void kernel_launch(void* const* d_in, const int* in_sizes, int n_in,
                              void* d_out, int out_size, void* d_ws, size_t ws_size,
                              hipStream_t stream) {
  const float* F = (const float*)d_in[0];
  float* out = (float*)d_out;
  const size_t imgBytes = (size_t)BATCH * NPIX * CH;   // fp8 image = 8.4 MB

  unsigned char* KAi = (unsigned char*)d_ws;
  __bf16* KBi = (__bf16*)((char*)d_ws + imgBytes);     // bf16 image = 16.8 MB
  ca_prep<<<dim3(BATCH, 128), 256, 0, stream>>>(F, KAi, KBi);
  ca_attn13<<<dim3(BATCH, 32), 1024, 0, stream>>>(F, KAi, KBi, out);
}